// Round 4
// baseline (314.187 us; speedup 1.0000x reference)
//
#include <hip/hip_runtime.h>
#include <hip/hip_bf16.h>
#include <math.h>

#define NB 16
#define NL 2048
#define ND 128
#define QT 64
#define KT 32
#define NTILE (NL / KT)            // 64 tiles per batch
#define NEGV -1000000.0f
#define SCL 0.08838834764831845f   // 1/sqrt(128)

typedef short bfrag __attribute__((ext_vector_type(8)));   // 8 bf16 (MFMA A/B frag)
typedef float f32x4 __attribute__((ext_vector_type(4)));
typedef short s16x4 __attribute__((ext_vector_type(4)));
typedef short s16x8 __attribute__((ext_vector_type(8)));

typedef const __attribute__((address_space(1))) void* gas_ptr;
typedef __attribute__((address_space(3))) void* las_ptr;

__device__ __forceinline__ short f2bf(float f) {
    unsigned u = __float_as_uint(f);
    unsigned r = u + 0x7FFFu + ((u >> 16) & 1u);
    return (short)(r >> 16);
}
__device__ __forceinline__ float bf2f(short h) {
    return __uint_as_float(((unsigned)(unsigned short)h) << 16);
}

__device__ __forceinline__ int kswz(int r, int c) { return (r * ND + c) ^ ((r & 7) << 3); }
__device__ __forceinline__ int vswz(int d, int k) { return (d * KT + k) ^ (((d >> 1) & 3) << 3); }
__device__ __forceinline__ int pswz(int q, int k) { return (q * KT + k) ^ (((q >> 1) & 3) << 3); }

// ===================== prep: K and V -> swizzled hi/lo bf16 tiles (mask-aware) ==
// KWS tile[kswz(r,c)] = bf16(K[r][c]); VWS tile[vswz(d,k)] = bf16(V[kt0+k][d])
__global__ __launch_bounds__(512) void prep_kv(const float* __restrict__ Kg,
                                               const float* __restrict__ Vg,
                                               const int* __restrict__ vlens,
                                               short* __restrict__ KWS,
                                               short* __restrict__ VWS) {
    const int bid = blockIdx.x;               // b*128 + t*2 + isv
    const int b = bid >> 7, rem = bid & 127, t = rem >> 1, isv = rem & 1;
    const int vlen = vlens[b];
    const int kmax = (vlen > 0) ? vlen : NL;
    if (t * KT >= kmax) return;               // masked-dead tile: never read
    const int g = threadIdx.x;
    const size_t bt = (size_t)(b * NTILE + t);
    if (!isv) {
        const int r = g >> 4, ccd = g & 15;
        const int ccs = ccd ^ (r & 7);        // inverse swizzle on source
        const float* src = Kg + ((size_t)b * NL + (size_t)(t * KT + r)) * ND + ccs * 8;
        f32x4 a0 = *(const f32x4*)src;
        f32x4 a1 = *(const f32x4*)(src + 4);
        float vals[8] = {a0[0], a0[1], a0[2], a0[3], a1[0], a1[1], a1[2], a1[3]};
        s16x8 h, l;
        #pragma unroll
        for (int j = 0; j < 8; ++j) {
            short hb = f2bf(vals[j]);
            h[j] = hb;
            l[j] = f2bf(vals[j] - bf2f(hb));
        }
        short* dst = KWS + bt * 8192 + g * 8;
        *(s16x8*)dst = h;
        *(s16x8*)(dst + 4096) = l;
    } else {
        const int ch = g >> 7, d = g & 127;
        const int chs = ch ^ ((d >> 1) & 3);
        const float* src = Vg + ((size_t)b * NL + (size_t)(t * KT + chs * 8)) * ND + d;
        s16x8 h, l;
        #pragma unroll
        for (int j = 0; j < 8; ++j) {
            float f = src[(size_t)j * ND];
            short hb = f2bf(f);
            h[j] = hb;
            l[j] = f2bf(f - bf2f(hb));
        }
        short* dst = VWS + bt * 8192 + (d * 4 + ch) * 8;
        *(s16x8*)dst = h;
        *(s16x8*)(dst + 4096) = l;
    }
}

// ===================== split flash attention: partials to PWS ====================
// PWS per unit (b,qblk,h): m[64], l[64], O[64][128] fp32 (unnormalized)
template<int NS>
__global__ __launch_bounds__(256, 4) void attn_split(
    const float* __restrict__ Qg, const int* __restrict__ vlens,
    const short* __restrict__ KWS, const short* __restrict__ VWS,
    float* __restrict__ PWS)
{
    constexpr int TPH = NTILE / NS;          // tiles per chunk
    constexpr int CHUNK = NB * 32 * NS / 8;  // wgids per XCD
    __shared__ __align__(16) short kv[4][4096];          // kh,kl,vh,vl  32KB
    __shared__ __align__(16) short ph[4][512], pl[4][512];  // 8KB

    const int tid = threadIdx.x;
    const int wv = tid >> 6, lane = tid & 63;
    const int lq = lane & 15, lg = lane >> 4;

    const int wg = blockIdx.x;
    const int wgid = (wg & 7) * CHUNK + (wg >> 3);       // bijective XCD swizzle
    const int b = wgid / (32 * NS);
    const int rem = wgid - b * (32 * NS);
    const int qblk = rem / NS;
    const int hh = rem - qblk * NS;

    const int vlen = vlens[b];
    const int kmax = (vlen > 0) ? vlen : NL;
    const int nt = (kmax + KT - 1) / KT;
    const int t0 = hh * TPH;
    const int t1 = (nt < t0 + TPH) ? nt : (t0 + TPH);
    if (t0 >= t1) return;                     // empty chunk (merge skips it); block-uniform

    const int q0 = qblk * QT + wv * 16;

    // ---- Q fragments hi/lo: lane holds Q[q0+lq][s*32 + lg*8 + j]
    bfrag qh[4], ql[4];
    {
        const float* qp = Qg + ((size_t)b * NL + (size_t)(q0 + lq)) * ND + lg * 8;
        #pragma unroll
        for (int s = 0; s < 4; ++s) {
            f32x4 a0 = *(const f32x4*)(qp + s * 32);
            f32x4 a1 = *(const f32x4*)(qp + s * 32 + 4);
            float vals[8] = {a0[0], a0[1], a0[2], a0[3], a1[0], a1[1], a1[2], a1[3]};
            bfrag h, l;
            #pragma unroll
            for (int j = 0; j < 8; ++j) {
                short hb = f2bf(vals[j]);
                h[j] = hb;
                l[j] = f2bf(vals[j] - bf2f(hb));
            }
            qh[s] = h; ql[s] = l;
        }
    }

    // wave wv stages array wv: 0=kh 1=kl 2=vh 3=vl
    const short* src = (wv < 2 ? KWS : VWS) + (size_t)b * NTILE * 8192
                     + (size_t)(wv & 1) * 4096 + lane * 8
                     + (size_t)t0 * 8192;

    // register prefetch of tile t0
    s16x8 pf[8];
    #pragma unroll
    for (int i = 0; i < 8; ++i)
        pf[i] = *(const s16x8*)(src + i * 512);

    const f32x4 zero4 = {0.f, 0.f, 0.f, 0.f};
    float m_run = -INFINITY, l_run = 0.0f;
    f32x4 oacc[8];
    #pragma unroll
    for (int i = 0; i < 8; ++i) oacc[i] = zero4;

    for (int t = t0; t < t1; ++t) {
        const int kt0 = t * KT;

        __builtin_amdgcn_s_barrier();         // all waves done reading prev tile
        #pragma unroll
        for (int i = 0; i < 8; ++i)           // regs (vmcnt auto-waited) -> LDS
            *(s16x8*)&kv[wv][i * 512 + lane * 8] = pf[i];
        asm volatile("s_waitcnt lgkmcnt(0)" ::: "memory");
        __builtin_amdgcn_sched_barrier(0);
        __builtin_amdgcn_s_barrier();         // tile t visible to all waves

        src += 8192;
        if (t + 1 < t1) {                     // issue next-tile loads (hidden under compute)
            #pragma unroll
            for (int i = 0; i < 8; ++i)
                pf[i] = *(const s16x8*)(src + i * 512);
        }

        // ---- QK^T (swapped): S^T[k][q]; split KhQh + KlQh + KhQl
        f32x4 sacc[2];
        sacc[0] = zero4; sacc[1] = zero4;
        #pragma unroll
        for (int sub = 0; sub < 2; ++sub) {
            #pragma unroll
            for (int s = 0; s < 4; ++s) {
                int ia = kswz(sub * 16 + lq, s * 32 + lg * 8);
                bfrag ah = *(const bfrag*)&kv[0][ia];
                bfrag al = *(const bfrag*)&kv[1][ia];
                sacc[sub] = __builtin_amdgcn_mfma_f32_16x16x32_bf16(ah, qh[s], sacc[sub], 0, 0, 0);
                sacc[sub] = __builtin_amdgcn_mfma_f32_16x16x32_bf16(al, qh[s], sacc[sub], 0, 0, 0);
                sacc[sub] = __builtin_amdgcn_mfma_f32_16x16x32_bf16(ah, ql[s], sacc[sub], 0, 0, 0);
            }
        }

        // ---- scale + exact -1e6 mask + online softmax with defer-max (THR=8)
        float sv[2][4];
        float tmax = -INFINITY;
        #pragma unroll
        for (int sub = 0; sub < 2; ++sub)
            #pragma unroll
            for (int r = 0; r < 4; ++r) {
                int kg = kt0 + sub * 16 + lg * 4 + r;
                float x = (kg < vlen) ? sacc[sub][r] * SCL : NEGV;
                sv[sub][r] = x;
                tmax = fmaxf(tmax, x);
            }
        tmax = fmaxf(tmax, __shfl_xor(tmax, 16, 64));
        tmax = fmaxf(tmax, __shfl_xor(tmax, 32, 64));
        if (!__all(tmax <= m_run + 8.0f)) {   // rescale only when max grew
            float m_new = fmaxf(m_run, tmax);
            float corr = __expf(m_run - m_new);   // first tile: exp(-inf)=0
            l_run *= corr;
            #pragma unroll
            for (int i = 0; i < 8; ++i) {
                oacc[i][0] *= corr; oacc[i][1] *= corr;
                oacc[i][2] *= corr; oacc[i][3] *= corr;
            }
            m_run = m_new;
        }
        float rsum = 0.f;
        s16x4 phv[2], plv[2];
        #pragma unroll
        for (int sub = 0; sub < 2; ++sub)
            #pragma unroll
            for (int r = 0; r < 4; ++r) {
                float p = __expf(sv[sub][r] - m_run);   // bounded by e^8
                rsum += p;
                short hb = f2bf(p);
                phv[sub][r] = hb;
                plv[sub][r] = f2bf(p - bf2f(hb));
            }
        rsum += __shfl_xor(rsum, 16, 64);
        rsum += __shfl_xor(rsum, 32, 64);
        l_run += rsum;

        // ---- P -> per-wave LDS (hi/lo), read back as PV B-operand
        #pragma unroll
        for (int sub = 0; sub < 2; ++sub) {
            int ip = pswz(lq, sub * 16 + lg * 4);
            *(s16x4*)&ph[wv][ip] = phv[sub];
            *(s16x4*)&pl[wv][ip] = plv[sub];
        }
        int ipb = pswz(lq, lg * 8);
        bfrag pbh = *(const bfrag*)&ph[wv][ipb];
        bfrag pbl = *(const bfrag*)&pl[wv][ipb];

        // ---- PV (swapped): O^T[d][q] += V^T hi/lo x P hi/lo (3 terms)
        #pragma unroll
        for (int dt = 0; dt < 8; ++dt) {
            int iv = vswz(dt * 16 + lq, lg * 8);
            bfrag vh  = *(const bfrag*)&kv[2][iv];
            bfrag vlo = *(const bfrag*)&kv[3][iv];
            oacc[dt] = __builtin_amdgcn_mfma_f32_16x16x32_bf16(vh,  pbh, oacc[dt], 0, 0, 0);
            oacc[dt] = __builtin_amdgcn_mfma_f32_16x16x32_bf16(vlo, pbh, oacc[dt], 0, 0, 0);
            oacc[dt] = __builtin_amdgcn_mfma_f32_16x16x32_bf16(vh,  pbl, oacc[dt], 0, 0, 0);
        }
    }

    // ---- write partial (m, l, unnormalized O)
    const size_t unit = (size_t)(b * 32 + qblk) * NS + hh;
    float* pw = PWS + unit * (128 + 64 * 128);
    if (lg == 0) {
        pw[wv * 16 + lq] = m_run;
        pw[64 + wv * 16 + lq] = l_run;
    }
    float* po = pw + 128 + (size_t)(wv * 16 + lq) * 128 + lg * 4;
    #pragma unroll
    for (int dt = 0; dt < 8; ++dt)
        *(f32x4*)(po + dt * 16) = oacc[dt];
}

// ===================== merge partials =====================
template<int NS>
__global__ __launch_bounds__(256) void merge_part(
    const int* __restrict__ vlens, const float* __restrict__ PWS,
    float* __restrict__ Og)
{
    constexpr int TPH = NTILE / NS;
    const int bid = blockIdx.x;               // b*32 + qblk
    const int b = bid >> 5, qblk = bid & 31;
    const int vlen = vlens[b];
    const int kmax = (vlen > 0) ? vlen : NL;
    const int nt = (kmax + KT - 1) / KT;
    int nh = (nt + TPH - 1) / TPH;
    if (nh > NS) nh = NS;

    const int tid = threadIdx.x;
    const int q = tid >> 2;                   // 64 q rows
    const int d0 = (tid & 3) * 32;

    const float* base = PWS + (size_t)((b * 32 + qblk) * NS) * (128 + 64 * 128);

    float mh[NS], lh[NS];
    float M = -INFINITY;
    #pragma unroll
    for (int h = 0; h < NS; ++h) {
        if (h < nh) {
            const float* pw = base + (size_t)h * (128 + 64 * 128);
            mh[h] = pw[q];
            lh[h] = pw[64 + q];
        } else { mh[h] = -INFINITY; lh[h] = 0.f; }
        M = fmaxf(M, mh[h]);
    }
    float w[NS];
    float L = 0.f;
    #pragma unroll
    for (int h = 0; h < NS; ++h) {
        w[h] = __expf(mh[h] - M);             // inactive: exp(-inf)=0
        L += lh[h] * w[h];
    }
    const float inv = 1.0f / L;

    float* out = Og + ((size_t)b * NL + (size_t)(qblk * 64 + q)) * ND + d0;
    #pragma unroll
    for (int c = 0; c < 8; ++c) {
        f32x4 acc = {0.f, 0.f, 0.f, 0.f};
        #pragma unroll
        for (int h = 0; h < NS; ++h) {
            if (h < nh) {
                const float* po = base + (size_t)h * (128 + 64 * 128) + 128
                                + (size_t)q * 128 + d0 + c * 4;
                f32x4 v = *(const f32x4*)po;
                acc[0] += v[0] * w[h]; acc[1] += v[1] * w[h];
                acc[2] += v[2] * w[h]; acc[3] += v[3] * w[h];
            }
        }
        acc[0] *= inv; acc[1] *= inv; acc[2] *= inv; acc[3] *= inv;
        *(f32x4*)(out + c * 4) = acc;
    }
}

// ===================== no-split fallback (round-2 kernel) ========================
__global__ __launch_bounds__(256, 2) void attn_fwd(
    const float* __restrict__ Qg, const int* __restrict__ vlens,
    const short* __restrict__ KWS, const short* __restrict__ VWS,
    float* __restrict__ Og)
{
    __shared__ __align__(16) short kv[2][4][4096];
    __shared__ __align__(16) short ph[4][512], pl[4][512];

    const int tid = threadIdx.x;
    const int wv = tid >> 6, lane = tid & 63;
    const int lq = lane & 15, lg = lane >> 4;

    const int bid = blockIdx.x;
    const int xcd = bid & 7, slot = bid >> 3;
    const int b = xcd * 2 + (slot >> 5);
    const int qblk = slot & 31;
    const int q0 = qblk * QT + wv * 16;

    const int vlen = vlens[b];
    const int kmax = (vlen > 0) ? vlen : NL;
    const int ntiles = (kmax + KT - 1) / KT;

    bfrag qh[4], ql[4];
    {
        const float* qp = Qg + ((size_t)b * NL + (size_t)(q0 + lq)) * ND + lg * 8;
        #pragma unroll
        for (int s = 0; s < 4; ++s) {
            f32x4 a0 = *(const f32x4*)(qp + s * 32);
            f32x4 a1 = *(const f32x4*)(qp + s * 32 + 4);
            float vals[8] = {a0[0], a0[1], a0[2], a0[3], a1[0], a1[1], a1[2], a1[3]};
            bfrag h, l;
            #pragma unroll
            for (int j = 0; j < 8; ++j) {
                short hb = f2bf(vals[j]);
                h[j] = hb;
                l[j] = f2bf(vals[j] - bf2f(hb));
            }
            qh[s] = h; ql[s] = l;
        }
    }

    const short* kws = KWS + (size_t)b * NTILE * 8192;
    const short* vws = VWS + (size_t)b * NTILE * 8192;
    const short* src_base = (wv < 2 ? kws : vws);
    const int hl = wv & 1;

    const f32x4 zero4 = {0.f, 0.f, 0.f, 0.f};
    float m_run = -INFINITY, l_run = 0.0f;
    f32x4 oacc[8];
    #pragma unroll
    for (int i = 0; i < 8; ++i) oacc[i] = zero4;

    int cur = 0;
    {
        const short* s0 = src_base + (size_t)hl * 4096 + lane * 8;
        #pragma unroll
        for (int i = 0; i < 8; ++i)
            __builtin_amdgcn_global_load_lds((gas_ptr)(s0 + i * 512),
                                             (las_ptr)(&kv[0][wv][i * 512]), 16, 0, 0);
    }

    for (int t = 0; t < ntiles; ++t) {
        const int kt0 = t * KT;
        if (t + 1 < ntiles) {
            const short* sn = src_base + ((size_t)(t + 1) * 2 + hl) * 4096 + lane * 8;
            #pragma unroll
            for (int i = 0; i < 8; ++i)
                __builtin_amdgcn_global_load_lds((gas_ptr)(sn + i * 512),
                                                 (las_ptr)(&kv[cur ^ 1][wv][i * 512]), 16, 0, 0);
            asm volatile("s_waitcnt vmcnt(8)" ::: "memory");
        } else {
            asm volatile("s_waitcnt vmcnt(0)" ::: "memory");
        }
        __builtin_amdgcn_s_barrier();
        asm volatile("" ::: "memory");

        f32x4 sacc[2];
        sacc[0] = zero4; sacc[1] = zero4;
        #pragma unroll
        for (int sub = 0; sub < 2; ++sub) {
            #pragma unroll
            for (int s = 0; s < 4; ++s) {
                int ia = kswz(sub * 16 + lq, s * 32 + lg * 8);
                bfrag ah = *(const bfrag*)&kv[cur][0][ia];
                bfrag al = *(const bfrag*)&kv[cur][1][ia];
                sacc[sub] = __builtin_amdgcn_mfma_f32_16x16x32_bf16(ah, qh[s], sacc[sub], 0, 0, 0);
                sacc[sub] = __builtin_amdgcn_mfma_f32_16x16x32_bf16(al, qh[s], sacc[sub], 0, 0, 0);
                sacc[sub] = __builtin_amdgcn_mfma_f32_16x16x32_bf16(ah, ql[s], sacc[sub], 0, 0, 0);
            }
        }

        float sv[2][4];
        float tmax = -INFINITY;
        #pragma unroll
        for (int sub = 0; sub < 2; ++sub)
            #pragma unroll
            for (int r = 0; r < 4; ++r) {
                int kg = kt0 + sub * 16 + lg * 4 + r;
                float x = (kg < vlen) ? sacc[sub][r] * SCL : NEGV;
                sv[sub][r] = x;
                tmax = fmaxf(tmax, x);
            }
        tmax = fmaxf(tmax, __shfl_xor(tmax, 16, 64));
        tmax = fmaxf(tmax, __shfl_xor(tmax, 32, 64));
        float m_new = fmaxf(m_run, tmax);
        float corr = __expf(m_run - m_new);
        float rsum = 0.f;
        s16x4 phv[2], plv[2];
        #pragma unroll
        for (int sub = 0; sub < 2; ++sub)
            #pragma unroll
            for (int r = 0; r < 4; ++r) {
                float p = __expf(sv[sub][r] - m_new);
                rsum += p;
                short hb = f2bf(p);
                phv[sub][r] = hb;
                plv[sub][r] = f2bf(p - bf2f(hb));
            }
        rsum += __shfl_xor(rsum, 16, 64);
        rsum += __shfl_xor(rsum, 32, 64);
        l_run = l_run * corr + rsum;
        m_run = m_new;
        #pragma unroll
        for (int i = 0; i < 8; ++i) {
            oacc[i][0] *= corr; oacc[i][1] *= corr;
            oacc[i][2] *= corr; oacc[i][3] *= corr;
        }

        #pragma unroll
        for (int sub = 0; sub < 2; ++sub) {
            int ip = pswz(lq, sub * 16 + lg * 4);
            *(s16x4*)&ph[wv][ip] = phv[sub];
            *(s16x4*)&pl[wv][ip] = plv[sub];
        }
        int ipb = pswz(lq, lg * 8);
        bfrag pbh = *(const bfrag*)&ph[wv][ipb];
        bfrag pbl = *(const bfrag*)&pl[wv][ipb];

        #pragma unroll
        for (int dt = 0; dt < 8; ++dt) {
            int iv = vswz(dt * 16 + lq, lg * 8);
            bfrag vh  = *(const bfrag*)&kv[cur][2][iv];
            bfrag vlo = *(const bfrag*)&kv[cur][3][iv];
            oacc[dt] = __builtin_amdgcn_mfma_f32_16x16x32_bf16(vh,  pbh, oacc[dt], 0, 0, 0);
            oacc[dt] = __builtin_amdgcn_mfma_f32_16x16x32_bf16(vlo, pbh, oacc[dt], 0, 0, 0);
            oacc[dt] = __builtin_amdgcn_mfma_f32_16x16x32_bf16(vh,  pbl, oacc[dt], 0, 0, 0);
        }

        asm volatile("" ::: "memory");
        __builtin_amdgcn_s_barrier();
        cur ^= 1;
    }

    float inv = 1.0f / l_run;
    float* op = Og + ((size_t)b * NL + (size_t)(q0 + lq)) * ND + lg * 4;
    #pragma unroll
    for (int dt = 0; dt < 8; ++dt) {
        f32x4 o;
        o[0] = oacc[dt][0] * inv; o[1] = oacc[dt][1] * inv;
        o[2] = oacc[dt][2] * inv; o[3] = oacc[dt][3] * inv;
        *(f32x4*)(op + dt * 16) = o;
    }
}

// ===================== last-resort fallback (round-1 kernel) =====================
__global__ __launch_bounds__(256, 2) void attn_fwd_fb(
    const float* __restrict__ Qg, const float* __restrict__ Kg,
    const float* __restrict__ Vg, const int* __restrict__ vlens,
    float* __restrict__ Og)
{
    __shared__ __align__(16) short kh[KT * ND], kl[KT * ND];
    __shared__ __align__(16) short vth[ND * KT], vtl[ND * KT];
    __shared__ __align__(16) short ph[4][16 * KT], pl[4][16 * KT];

    const int tid = threadIdx.x;
    const int wv = tid >> 6, lane = tid & 63;
    const int lq = lane & 15, lg = lane >> 4;
    const int bid = blockIdx.x;
    const int b = bid >> 5;
    const int qblk = bid & 31;
    const int q0 = qblk * QT + wv * 16;
    const int vlen = vlens[b];
    const int kmax = (vlen > 0) ? vlen : NL;
    const int ntiles = (kmax + KT - 1) / KT;

    bfrag qh[4], ql[4];
    {
        const float* qp = Qg + ((size_t)b * NL + (size_t)(q0 + lq)) * ND + lg * 8;
        #pragma unroll
        for (int s = 0; s < 4; ++s) {
            f32x4 a0 = *(const f32x4*)(qp + s * 32);
            f32x4 a1 = *(const f32x4*)(qp + s * 32 + 4);
            float vals[8] = {a0[0], a0[1], a0[2], a0[3], a1[0], a1[1], a1[2], a1[3]};
            bfrag h, l;
            #pragma unroll
            for (int j = 0; j < 8; ++j) {
                short hb = f2bf(vals[j]);
                h[j] = hb;
                l[j] = f2bf(vals[j] - bf2f(hb));
            }
            qh[s] = h; ql[s] = l;
        }
    }

    const f32x4 zero4 = {0.f, 0.f, 0.f, 0.f};
    float m_run = -INFINITY, l_run = 0.0f;
    f32x4 oacc[8];
    #pragma unroll
    for (int i = 0; i < 8; ++i) oacc[i] = zero4;

    const float* kbase = Kg + (size_t)b * NL * ND;
    const float* vbase = Vg + (size_t)b * NL * ND;

    for (int t = 0; t < ntiles; ++t) {
        const int kt0 = t * KT;
        __syncthreads();
        #pragma unroll
        for (int i = 0; i < 4; ++i) {
            int f = i * 256 + tid;
            int r = f >> 5, c4 = (f & 31) << 2;
            f32x4 v = *(const f32x4*)(kbase + (size_t)(kt0 + r) * ND + c4);
            s16x4 hh, ll;
            #pragma unroll
            for (int j = 0; j < 4; ++j) {
                short hb = f2bf(v[j]);
                hh[j] = hb;
                ll[j] = f2bf(v[j] - bf2f(hb));
            }
            int idx = kswz(r, c4);
            *(s16x4*)&kh[idx] = hh;
            *(s16x4*)&kl[idx] = ll;
        }
        #pragma unroll
        for (int i = 0; i < 4; ++i) {
            int tau = i * 256 + tid;
            int c = tau & 127, kq = (tau >> 7) << 2;
            s16x4 hh, ll;
            #pragma unroll
            for (int j = 0; j < 4; ++j) {
                float fv = vbase[(size_t)(kt0 + kq + j) * ND + c];
                short hb = f2bf(fv);
                hh[j] = hb;
                ll[j] = f2bf(fv - bf2f(hb));
            }
            int idx = vswz(c, kq);
            *(s16x4*)&vth[idx] = hh;
            *(s16x4*)&vtl[idx] = ll;
        }
        __syncthreads();

        f32x4 sacc[2];
        sacc[0] = zero4; sacc[1] = zero4;
        #pragma unroll
        for (int sub = 0; sub < 2; ++sub) {
            #pragma unroll
            for (int s = 0; s < 4; ++s) {
                int ia = kswz(sub * 16 + lq, s * 32 + lg * 8);
                bfrag ah = *(const bfrag*)&kh[ia];
                bfrag al = *(const bfrag*)&kl[ia];
                sacc[sub] = __builtin_amdgcn_mfma_f32_16x16x32_bf16(ah, qh[s], sacc[sub], 0, 0, 0);
                sacc[sub] = __builtin_amdgcn_mfma_f32_16x16x32_bf16(al, qh[s], sacc[sub], 0, 0, 0);
                sacc[sub] = __builtin_amdgcn_mfma_f32_16x16x32_bf16(ah, ql[s], sacc[sub], 0, 0, 0);
            }
        }

        float sv[2][4];
        float tmax = -INFINITY;
        #pragma unroll
        for (int sub = 0; sub < 2; ++sub)
            #pragma unroll
            for (int r = 0; r < 4; ++r) {
                int kg = kt0 + sub * 16 + lg * 4 + r;
                float x = (kg < vlen) ? sacc[sub][r] * SCL : NEGV;
                sv[sub][r] = x;
                tmax = fmaxf(tmax, x);
            }
        tmax = fmaxf(tmax, __shfl_xor(tmax, 16, 64));
        tmax = fmaxf(tmax, __shfl_xor(tmax, 32, 64));
        float m_new = fmaxf(m_run, tmax);
        float corr = __expf(m_run - m_new);
        float rsum = 0.f;
        s16x4 phv[2], plv[2];
        #pragma unroll
        for (int sub = 0; sub < 2; ++sub)
            #pragma unroll
            for (int r = 0; r < 4; ++r) {
                float p = __expf(sv[sub][r] - m_new);
                rsum += p;
                short hb = f2bf(p);
                phv[sub][r] = hb;
                plv[sub][r] = f2bf(p - bf2f(hb));
            }
        rsum += __shfl_xor(rsum, 16, 64);
        rsum += __shfl_xor(rsum, 32, 64);
        l_run = l_run * corr + rsum;
        m_run = m_new;
        #pragma unroll
        for (int i = 0; i < 8; ++i) {
            oacc[i][0] *= corr; oacc[i][1] *= corr;
            oacc[i][2] *= corr; oacc[i][3] *= corr;
        }

        #pragma unroll
        for (int sub = 0; sub < 2; ++sub) {
            int ip = pswz(lq, sub * 16 + lg * 4);
            *(s16x4*)&ph[wv][ip] = phv[sub];
            *(s16x4*)&pl[wv][ip] = plv[sub];
        }
        int ipb = pswz(lq, lg * 8);
        bfrag pbh = *(const bfrag*)&ph[wv][ipb];
        bfrag pbl = *(const bfrag*)&pl[wv][ipb];
        #pragma unroll
        for (int dt = 0; dt < 8; ++dt) {
            int iv = vswz(dt * 16 + lq, lg * 8);
            bfrag vh  = *(const bfrag*)&vth[iv];
            bfrag vlo = *(const bfrag*)&vtl[iv];
            oacc[dt] = __builtin_amdgcn_mfma_f32_16x16x32_bf16(vh,  pbh, oacc[dt], 0, 0, 0);
            oacc[dt] = __builtin_amdgcn_mfma_f32_16x16x32_bf16(vlo, pbh, oacc[dt], 0, 0, 0);
            oacc[dt] = __builtin_amdgcn_mfma_f32_16x16x32_bf16(vh,  pbl, oacc[dt], 0, 0, 0);
        }
    }

    float inv = 1.0f / l_run;
    float* op = Og + ((size_t)b * NL + (size_t)(q0 + lq)) * ND + lg * 4;
    #pragma unroll
    for (int dt = 0; dt < 8; ++dt) {
        f32x4 o;
        o[0] = oacc[dt][0] * inv; o[1] = oacc[dt][1] * inv;
        o[2] = oacc[dt][2] * inv; o[3] = oacc[dt][3] * inv;
        *(f32x4*)(op + dt * 16) = o;
    }
}

extern "C" void kernel_launch(void* const* d_in, const int* in_sizes, int n_in,
                              void* d_out, int out_size, void* d_ws, size_t ws_size,
                              hipStream_t stream) {
    (void)in_sizes; (void)n_in; (void)out_size;
    const float* Q = (const float*)d_in[0];
    const float* K = (const float*)d_in[1];
    const float* V = (const float*)d_in[2];
    const int* vl  = (const int*)d_in[3];
    float* O = (float*)d_out;

    const size_t tensor_shorts = (size_t)NB * NTILE * 8192;            // per K or V ws
    const size_t kv_bytes = 2 * tensor_shorts * sizeof(short);         // 33.55 MB
    const size_t unit_floats = 128 + 64 * 128;                         // 8320
    const size_t pws4 = (size_t)NB * 32 * 4 * unit_floats * 4;         // 68.2 MB
    const size_t pws2 = (size_t)NB * 32 * 2 * unit_floats * 4;         // 34.1 MB

    short* KWS = (short*)d_ws;
    short* VWS = KWS + tensor_shorts;
    float* PWS = (float*)((char*)d_ws + kv_bytes);

    if (ws_size >= kv_bytes + pws4) {
        prep_kv<<<dim3(NB * NTILE * 2), dim3(512), 0, stream>>>(K, V, vl, KWS, VWS);
        attn_split<4><<<dim3(NB * 32 * 4), dim3(256), 0, stream>>>(Q, vl, KWS, VWS, PWS);
        merge_part<4><<<dim3(NB * 32), dim3(256), 0, stream>>>(vl, PWS, O);
    } else if (ws_size >= kv_bytes + pws2) {
        prep_kv<<<dim3(NB * NTILE * 2), dim3(512), 0, stream>>>(K, V, vl, KWS, VWS);
        attn_split<2><<<dim3(NB * 32 * 2), dim3(256), 0, stream>>>(Q, vl, KWS, VWS, PWS);
        merge_part<2><<<dim3(NB * 32), dim3(256), 0, stream>>>(vl, PWS, O);
    } else if (ws_size >= kv_bytes) {
        prep_kv<<<dim3(NB * NTILE * 2), dim3(512), 0, stream>>>(K, V, vl, KWS, VWS);
        attn_fwd<<<dim3(NB * (NL / QT)), dim3(256), 0, stream>>>(Q, vl, KWS, VWS, O);
    } else {
        attn_fwd_fb<<<dim3(NB * (NL / QT)), dim3(256), 0, stream>>>(Q, K, V, vl, O);
    }
}

// Round 10
// 224.867 us; speedup vs baseline: 1.3972x; 1.3972x over previous
//
#include <hip/hip_runtime.h>
#include <hip/hip_bf16.h>
#include <math.h>

#define NB 16
#define NL 2048
#define ND 128
#define KT 32
#define NTILE (NL / KT)            // 64 tiles per batch
#define NEGV -1000000.0f
#define SCL 0.08838834764831845f   // 1/sqrt(128)

typedef short bfrag __attribute__((ext_vector_type(8)));   // 8 bf16 (MFMA A/B frag)
typedef float f32x4 __attribute__((ext_vector_type(4)));
typedef short s16x4 __attribute__((ext_vector_type(4)));
typedef short s16x8 __attribute__((ext_vector_type(8)));

typedef const __attribute__((address_space(1))) void* gas_ptr;
typedef __attribute__((address_space(3))) void* las_ptr;

__device__ __forceinline__ short f2bf(float f) {
    unsigned u = __float_as_uint(f);
    unsigned r = u + 0x7FFFu + ((u >> 16) & 1u);
    return (short)(r >> 16);
}
__device__ __forceinline__ float bf2f(short h) {
    return __uint_as_float(((unsigned)(unsigned short)h) << 16);
}

__device__ __forceinline__ int kswz(int r, int c) { return (r * ND + c) ^ ((r & 7) << 3); }
__device__ __forceinline__ int vswz(int d, int k) { return (d * KT + k) ^ (((d >> 1) & 3) << 3); }
__device__ __forceinline__ int pswz(int q, int k) { return (q * KT + k) ^ (((q >> 1) & 3) << 3); }

// ===================== prep: K and V -> swizzled hi/lo bf16 tiles (mask-aware) ==
__global__ __launch_bounds__(512) void prep_kv(const float* __restrict__ Kg,
                                               const float* __restrict__ Vg,
                                               const int* __restrict__ vlens,
                                               short* __restrict__ KWS,
                                               short* __restrict__ VWS) {
    const int bid = blockIdx.x;               // b*128 + t*2 + isv
    const int b = bid >> 7, rem = bid & 127, t = rem >> 1, isv = rem & 1;
    const int vlen = vlens[b];
    const int kmax = (vlen > 0) ? vlen : NL;
    if (t * KT >= kmax) return;               // masked-dead tile: never read
    const int g = threadIdx.x;
    const size_t bt = (size_t)(b * NTILE + t);
    if (!isv) {
        const int r = g >> 4, ccd = g & 15;
        const int ccs = ccd ^ (r & 7);        // inverse swizzle on source
        const float* src = Kg + ((size_t)b * NL + (size_t)(t * KT + r)) * ND + ccs * 8;
        f32x4 a0 = *(const f32x4*)src;
        f32x4 a1 = *(const f32x4*)(src + 4);
        float vals[8] = {a0[0], a0[1], a0[2], a0[3], a1[0], a1[1], a1[2], a1[3]};
        s16x8 h, l;
        #pragma unroll
        for (int j = 0; j < 8; ++j) {
            short hb = f2bf(vals[j]);
            h[j] = hb;
            l[j] = f2bf(vals[j] - bf2f(hb));
        }
        short* dst = KWS + bt * 8192 + g * 8;
        *(s16x8*)dst = h;
        *(s16x8*)(dst + 4096) = l;
    } else {
        const int ch = g >> 7, d = g & 127;
        const int chs = ch ^ ((d >> 1) & 3);
        const float* src = Vg + ((size_t)b * NL + (size_t)(t * KT + chs * 8)) * ND + d;
        s16x8 h, l;
        #pragma unroll
        for (int j = 0; j < 8; ++j) {
            float f = src[(size_t)j * ND];
            short hb = f2bf(f);
            h[j] = hb;
            l[j] = f2bf(f - bf2f(hb));
        }
        short* dst = VWS + bt * 8192 + (d * 4 + ch) * 8;
        *(s16x8*)dst = h;
        *(s16x8*)(dst + 4096) = l;
    }
}

// ============ 8-wave split flash attention (QT=128), dbuf global_load_lds =======
// PWS per unit (b,qblk,h): m[128], l[128], O[128][128] fp32 (unnormalized) = 16640 f
template<int NS>
__global__ __launch_bounds__(512, 4) void attn_split8(
    const float* __restrict__ Qg, const int* __restrict__ vlens,
    const short* __restrict__ KWS, const short* __restrict__ VWS,
    float* __restrict__ PWS)
{
    constexpr int TPH = NTILE / NS;
    constexpr int CHUNK = NB * 16 * NS / 8;
    __shared__ __align__(16) short kv[2][4][4096];          // dbuf kh,kl,vh,vl 64KB
    __shared__ __align__(16) short ph[8][512], pl[8][512];  // per-wave P hi/lo 16KB

    const int tid = threadIdx.x;
    const int wv = tid >> 6, lane = tid & 63;
    const int lq = lane & 15, lg = lane >> 4;

    const int wg = blockIdx.x;
    const int wgid = (wg & 7) * CHUNK + (wg >> 3);          // bijective XCD swizzle
    const int b = wgid / (16 * NS);
    const int rem = wgid - b * (16 * NS);
    const int qblk = rem / NS;
    const int hh = rem - qblk * NS;

    const int vlen = vlens[b];
    const int kmax = (vlen > 0) ? vlen : NL;                // vlen==0 -> uniform
    const int nt = (kmax + KT - 1) / KT;
    const int t0 = hh * TPH;
    const int t1 = (nt < t0 + TPH) ? nt : (t0 + TPH);
    if (t0 >= t1) return;                                   // block-uniform exit

    const int q0 = qblk * 128 + wv * 16;

    // ---- Q fragments hi/lo: lane holds Q[q0+lq][s*32 + lg*8 + j]
    bfrag qh[4], ql[4];
    {
        const float* qp = Qg + ((size_t)b * NL + (size_t)(q0 + lq)) * ND + lg * 8;
        #pragma unroll
        for (int s = 0; s < 4; ++s) {
            f32x4 a0 = *(const f32x4*)(qp + s * 32);
            f32x4 a1 = *(const f32x4*)(qp + s * 32 + 4);
            float vals[8] = {a0[0], a0[1], a0[2], a0[3], a1[0], a1[1], a1[2], a1[3]};
            bfrag h, l;
            #pragma unroll
            for (int j = 0; j < 8; ++j) {
                short hb = f2bf(vals[j]);
                h[j] = hb;
                l[j] = f2bf(vals[j] - bf2f(hb));
            }
            qh[s] = h; ql[s] = l;
        }
    }

    // staging: wave wv stages array arr=wv>>1 (0=kh 1=kl 2=vh 3=vl), half=wv&1 (4KB)
    const int arr = wv >> 1, half = wv & 1;
    const short* tsrc = (arr < 2 ? KWS : VWS)
                      + (size_t)(b * NTILE + t0) * 8192
                      + (size_t)(arr & 1) * 4096 + half * 2048 + lane * 8;

    const f32x4 zero4 = {0.f, 0.f, 0.f, 0.f};
    float m_run = -INFINITY, l_run = 0.0f;
    f32x4 oacc[8];
    #pragma unroll
    for (int i = 0; i < 8; ++i) oacc[i] = zero4;

    int cur = 0;
    // prologue: stage tile t0 into buf 0 (4 x 1KB wave-insts)
    #pragma unroll
    for (int i = 0; i < 4; ++i)
        __builtin_amdgcn_global_load_lds((gas_ptr)(tsrc + i * 512),
            (las_ptr)(&kv[0][arr][half * 2048 + i * 512]), 16, 0, 0);

    for (int t = t0; t < t1; ++t) {
        const int kt0 = t * KT;
        if (t + 1 < t1) {
            // prefetch next tile into other buffer (issued, counted-wait)
            const short* sn = tsrc + (size_t)(t + 1 - t0) * 8192;
            #pragma unroll
            for (int i = 0; i < 4; ++i)
                __builtin_amdgcn_global_load_lds((gas_ptr)(sn + i * 512),
                    (las_ptr)(&kv[cur ^ 1][arr][half * 2048 + i * 512]), 16, 0, 0);
            asm volatile("s_waitcnt vmcnt(4)" ::: "memory");  // tile-t's 4 done
        } else {
            asm volatile("s_waitcnt vmcnt(0)" ::: "memory");
        }
        __builtin_amdgcn_s_barrier();
        asm volatile("" ::: "memory");

        // ---- QK^T (swapped): S^T[k][q]; split KhQh + KlQh + KhQl
        f32x4 sacc[2];
        sacc[0] = zero4; sacc[1] = zero4;
        __builtin_amdgcn_s_setprio(1);
        #pragma unroll
        for (int sub = 0; sub < 2; ++sub) {
            #pragma unroll
            for (int s = 0; s < 4; ++s) {
                int ia = kswz(sub * 16 + lq, s * 32 + lg * 8);
                bfrag ah = *(const bfrag*)&kv[cur][0][ia];
                bfrag al = *(const bfrag*)&kv[cur][1][ia];
                sacc[sub] = __builtin_amdgcn_mfma_f32_16x16x32_bf16(ah, qh[s], sacc[sub], 0, 0, 0);
                sacc[sub] = __builtin_amdgcn_mfma_f32_16x16x32_bf16(al, qh[s], sacc[sub], 0, 0, 0);
                sacc[sub] = __builtin_amdgcn_mfma_f32_16x16x32_bf16(ah, ql[s], sacc[sub], 0, 0, 0);
            }
        }
        __builtin_amdgcn_s_setprio(0);

        // ---- scale + exact -1e6 mask + online softmax with defer-max (THR=8)
        float sv[2][4];
        float tmax = -INFINITY;
        #pragma unroll
        for (int sub = 0; sub < 2; ++sub)
            #pragma unroll
            for (int r = 0; r < 4; ++r) {
                int kg = kt0 + sub * 16 + lg * 4 + r;
                float x = (kg < vlen) ? sacc[sub][r] * SCL : NEGV;
                sv[sub][r] = x;
                tmax = fmaxf(tmax, x);
            }
        tmax = fmaxf(tmax, __shfl_xor(tmax, 16, 64));
        tmax = fmaxf(tmax, __shfl_xor(tmax, 32, 64));
        if (!__all(tmax <= m_run + 8.0f)) {   // rescale only when max grew
            float m_new = fmaxf(m_run, tmax);
            float corr = __expf(m_run - m_new);   // first tile: exp(-inf)=0
            l_run *= corr;
            #pragma unroll
            for (int i = 0; i < 8; ++i) {
                oacc[i][0] *= corr; oacc[i][1] *= corr;
                oacc[i][2] *= corr; oacc[i][3] *= corr;
            }
            m_run = m_new;
        }
        float rsum = 0.f;
        s16x4 phv[2], plv[2];
        #pragma unroll
        for (int sub = 0; sub < 2; ++sub)
            #pragma unroll
            for (int r = 0; r < 4; ++r) {
                float p = __expf(sv[sub][r] - m_run);   // bounded by e^8
                rsum += p;
                short hb = f2bf(p);
                phv[sub][r] = hb;
                plv[sub][r] = f2bf(p - bf2f(hb));
            }
        rsum += __shfl_xor(rsum, 16, 64);
        rsum += __shfl_xor(rsum, 32, 64);
        l_run += rsum;

        // ---- P -> per-wave LDS (hi/lo), read back as PV B-operand
        #pragma unroll
        for (int sub = 0; sub < 2; ++sub) {
            int ip = pswz(lq, sub * 16 + lg * 4);
            *(s16x4*)&ph[wv][ip] = phv[sub];
            *(s16x4*)&pl[wv][ip] = plv[sub];
        }
        int ipb = pswz(lq, lg * 8);
        bfrag pbh = *(const bfrag*)&ph[wv][ipb];
        bfrag pbl = *(const bfrag*)&pl[wv][ipb];

        // ---- PV (swapped): O^T[d][q] += V^T hi/lo x P hi/lo (3 terms)
        __builtin_amdgcn_s_setprio(1);
        #pragma unroll
        for (int dt = 0; dt < 8; ++dt) {
            int iv = vswz(dt * 16 + lq, lg * 8);
            bfrag vh  = *(const bfrag*)&kv[cur][2][iv];
            bfrag vlo = *(const bfrag*)&kv[cur][3][iv];
            oacc[dt] = __builtin_amdgcn_mfma_f32_16x16x32_bf16(vh,  pbh, oacc[dt], 0, 0, 0);
            oacc[dt] = __builtin_amdgcn_mfma_f32_16x16x32_bf16(vlo, pbh, oacc[dt], 0, 0, 0);
            oacc[dt] = __builtin_amdgcn_mfma_f32_16x16x32_bf16(vh,  pbl, oacc[dt], 0, 0, 0);
        }
        __builtin_amdgcn_s_setprio(0);

        asm volatile("" ::: "memory");
        __builtin_amdgcn_s_barrier();   // all waves done reading kv[cur]
        cur ^= 1;
    }

    // ---- write partial (m, l, unnormalized O); row = wv*16+lq in [0,128)
    const size_t unit = (size_t)((b * 16 + qblk) * NS + hh);
    float* pw = PWS + unit * 16640;
    if (lg == 0) {
        pw[wv * 16 + lq] = m_run;
        pw[128 + wv * 16 + lq] = l_run;
    }
    float* po = pw + 256 + (size_t)(wv * 16 + lq) * 128 + lg * 4;
    #pragma unroll
    for (int dt = 0; dt < 8; ++dt)
        *(f32x4*)(po + dt * 16) = oacc[dt];
}

// ===================== merge partials (QT=128 units) =====================
template<int NS>
__global__ __launch_bounds__(256) void merge_part8(
    const int* __restrict__ vlens, const float* __restrict__ PWS,
    float* __restrict__ Og)
{
    constexpr int TPH = NTILE / NS;
    const int bid = blockIdx.x;               // b*16 + qblk
    const int b = bid >> 4, qblk = bid & 15;
    const int vlen = vlens[b];
    const int kmax = (vlen > 0) ? vlen : NL;
    const int nt = (kmax + KT - 1) / KT;
    int nh = (nt + TPH - 1) / TPH;
    if (nh > NS) nh = NS;

    const int tid = threadIdx.x;
    const int q = tid >> 1;                   // 128 q rows
    const int dh = (tid & 1) * 64;

    const float* base = PWS + (size_t)(bid * NS) * 16640;

    float mh[NS], lh[NS];
    float M = -INFINITY;
    #pragma unroll
    for (int h = 0; h < NS; ++h) {
        if (h < nh) {
            const float* pw = base + (size_t)h * 16640;
            mh[h] = pw[q];
            lh[h] = pw[128 + q];
        } else { mh[h] = -INFINITY; lh[h] = 0.f; }
        M = fmaxf(M, mh[h]);
    }
    float w[NS];
    float L = 0.f;
    #pragma unroll
    for (int h = 0; h < NS; ++h) {
        w[h] = __expf(mh[h] - M);             // inactive: exp(-inf)=0
        L += lh[h] * w[h];
    }
    const float inv = 1.0f / L;

    float* out = Og + ((size_t)b * NL + (size_t)(qblk * 128 + q)) * ND + dh;
    #pragma unroll
    for (int c = 0; c < 16; ++c) {
        f32x4 acc = {0.f, 0.f, 0.f, 0.f};
        #pragma unroll
        for (int h = 0; h < NS; ++h) {
            if (h < nh) {
                const float* po = base + (size_t)h * 16640 + 256
                                + (size_t)q * 128 + dh + c * 4;
                f32x4 v = *(const f32x4*)po;
                acc[0] += v[0] * w[h]; acc[1] += v[1] * w[h];
                acc[2] += v[2] * w[h]; acc[3] += v[3] * w[h];
            }
        }
        acc[0] *= inv; acc[1] *= inv; acc[2] *= inv; acc[3] *= inv;
        *(f32x4*)(out + c * 4) = acc;
    }
}

// ===================== no-split fallback (round-2 kernel, 4-wave) ================
__global__ __launch_bounds__(256, 2) void attn_fwd(
    const float* __restrict__ Qg, const int* __restrict__ vlens,
    const short* __restrict__ KWS, const short* __restrict__ VWS,
    float* __restrict__ Og)
{
    __shared__ __align__(16) short kv[2][4][4096];
    __shared__ __align__(16) short ph[4][512], pl[4][512];

    const int tid = threadIdx.x;
    const int wv = tid >> 6, lane = tid & 63;
    const int lq = lane & 15, lg = lane >> 4;

    const int bid = blockIdx.x;
    const int xcd = bid & 7, slot = bid >> 3;
    const int b = xcd * 2 + (slot >> 5);
    const int qblk = slot & 31;
    const int q0 = qblk * 64 + wv * 16;

    const int vlen = vlens[b];
    const int kmax = (vlen > 0) ? vlen : NL;
    const int ntiles = (kmax + KT - 1) / KT;

    bfrag qh[4], ql[4];
    {
        const float* qp = Qg + ((size_t)b * NL + (size_t)(q0 + lq)) * ND + lg * 8;
        #pragma unroll
        for (int s = 0; s < 4; ++s) {
            f32x4 a0 = *(const f32x4*)(qp + s * 32);
            f32x4 a1 = *(const f32x4*)(qp + s * 32 + 4);
            float vals[8] = {a0[0], a0[1], a0[2], a0[3], a1[0], a1[1], a1[2], a1[3]};
            bfrag h, l;
            #pragma unroll
            for (int j = 0; j < 8; ++j) {
                short hb = f2bf(vals[j]);
                h[j] = hb;
                l[j] = f2bf(vals[j] - bf2f(hb));
            }
            qh[s] = h; ql[s] = l;
        }
    }

    const short* kws = KWS + (size_t)b * NTILE * 8192;
    const short* vws = VWS + (size_t)b * NTILE * 8192;
    const short* src_base = (wv < 2 ? kws : vws);
    const int hl = wv & 1;

    const f32x4 zero4 = {0.f, 0.f, 0.f, 0.f};
    float m_run = -INFINITY, l_run = 0.0f;
    f32x4 oacc[8];
    #pragma unroll
    for (int i = 0; i < 8; ++i) oacc[i] = zero4;

    int cur = 0;
    {
        const short* s0 = src_base + (size_t)hl * 4096 + lane * 8;
        #pragma unroll
        for (int i = 0; i < 8; ++i)
            __builtin_amdgcn_global_load_lds((gas_ptr)(s0 + i * 512),
                                             (las_ptr)(&kv[0][wv][i * 512]), 16, 0, 0);
    }

    for (int t = 0; t < ntiles; ++t) {
        const int kt0 = t * KT;
        if (t + 1 < ntiles) {
            const short* sn = src_base + ((size_t)(t + 1) * 2 + hl) * 4096 + lane * 8;
            #pragma unroll
            for (int i = 0; i < 8; ++i)
                __builtin_amdgcn_global_load_lds((gas_ptr)(sn + i * 512),
                                                 (las_ptr)(&kv[cur ^ 1][wv][i * 512]), 16, 0, 0);
            asm volatile("s_waitcnt vmcnt(8)" ::: "memory");
        } else {
            asm volatile("s_waitcnt vmcnt(0)" ::: "memory");
        }
        __builtin_amdgcn_s_barrier();
        asm volatile("" ::: "memory");

        f32x4 sacc[2];
        sacc[0] = zero4; sacc[1] = zero4;
        #pragma unroll
        for (int sub = 0; sub < 2; ++sub) {
            #pragma unroll
            for (int s = 0; s < 4; ++s) {
                int ia = kswz(sub * 16 + lq, s * 32 + lg * 8);
                bfrag ah = *(const bfrag*)&kv[cur][0][ia];
                bfrag al = *(const bfrag*)&kv[cur][1][ia];
                sacc[sub] = __builtin_amdgcn_mfma_f32_16x16x32_bf16(ah, qh[s], sacc[sub], 0, 0, 0);
                sacc[sub] = __builtin_amdgcn_mfma_f32_16x16x32_bf16(al, qh[s], sacc[sub], 0, 0, 0);
                sacc[sub] = __builtin_amdgcn_mfma_f32_16x16x32_bf16(ah, ql[s], sacc[sub], 0, 0, 0);
            }
        }

        float sv[2][4];
        float tmax = -INFINITY;
        #pragma unroll
        for (int sub = 0; sub < 2; ++sub)
            #pragma unroll
            for (int r = 0; r < 4; ++r) {
                int kg = kt0 + sub * 16 + lg * 4 + r;
                float x = (kg < vlen) ? sacc[sub][r] * SCL : NEGV;
                sv[sub][r] = x;
                tmax = fmaxf(tmax, x);
            }
        tmax = fmaxf(tmax, __shfl_xor(tmax, 16, 64));
        tmax = fmaxf(tmax, __shfl_xor(tmax, 32, 64));
        float m_new = fmaxf(m_run, tmax);
        float corr = __expf(m_run - m_new);
        float rsum = 0.f;
        s16x4 phv[2], plv[2];
        #pragma unroll
        for (int sub = 0; sub < 2; ++sub)
            #pragma unroll
            for (int r = 0; r < 4; ++r) {
                float p = __expf(sv[sub][r] - m_new);
                rsum += p;
                short hb = f2bf(p);
                phv[sub][r] = hb;
                plv[sub][r] = f2bf(p - bf2f(hb));
            }
        rsum += __shfl_xor(rsum, 16, 64);
        rsum += __shfl_xor(rsum, 32, 64);
        l_run = l_run * corr + rsum;
        m_run = m_new;
        #pragma unroll
        for (int i = 0; i < 8; ++i) {
            oacc[i][0] *= corr; oacc[i][1] *= corr;
            oacc[i][2] *= corr; oacc[i][3] *= corr;
        }

        #pragma unroll
        for (int sub = 0; sub < 2; ++sub) {
            int ip = pswz(lq, sub * 16 + lg * 4);
            *(s16x4*)&ph[wv][ip] = phv[sub];
            *(s16x4*)&pl[wv][ip] = plv[sub];
        }
        int ipb = pswz(lq, lg * 8);
        bfrag pbh = *(const bfrag*)&ph[wv][ipb];
        bfrag pbl = *(const bfrag*)&pl[wv][ipb];

        #pragma unroll
        for (int dt = 0; dt < 8; ++dt) {
            int iv = vswz(dt * 16 + lq, lg * 8);
            bfrag vh  = *(const bfrag*)&kv[cur][2][iv];
            bfrag vlo = *(const bfrag*)&kv[cur][3][iv];
            oacc[dt] = __builtin_amdgcn_mfma_f32_16x16x32_bf16(vh,  pbh, oacc[dt], 0, 0, 0);
            oacc[dt] = __builtin_amdgcn_mfma_f32_16x16x32_bf16(vlo, pbh, oacc[dt], 0, 0, 0);
            oacc[dt] = __builtin_amdgcn_mfma_f32_16x16x32_bf16(vh,  pbl, oacc[dt], 0, 0, 0);
        }

        asm volatile("" ::: "memory");
        __builtin_amdgcn_s_barrier();
        cur ^= 1;
    }

    float inv = 1.0f / l_run;
    float* op = Og + ((size_t)b * NL + (size_t)(q0 + lq)) * ND + lg * 4;
    #pragma unroll
    for (int dt = 0; dt < 8; ++dt) {
        f32x4 o;
        o[0] = oacc[dt][0] * inv; o[1] = oacc[dt][1] * inv;
        o[2] = oacc[dt][2] * inv; o[3] = oacc[dt][3] * inv;
        *(f32x4*)(op + dt * 16) = o;
    }
}

// ===================== last-resort fallback (round-1 kernel) =====================
__global__ __launch_bounds__(256, 2) void attn_fwd_fb(
    const float* __restrict__ Qg, const float* __restrict__ Kg,
    const float* __restrict__ Vg, const int* __restrict__ vlens,
    float* __restrict__ Og)
{
    __shared__ __align__(16) short kh[KT * ND], kl[KT * ND];
    __shared__ __align__(16) short vth[ND * KT], vtl[ND * KT];
    __shared__ __align__(16) short ph[4][16 * KT], pl[4][16 * KT];

    const int tid = threadIdx.x;
    const int wv = tid >> 6, lane = tid & 63;
    const int lq = lane & 15, lg = lane >> 4;
    const int bid = blockIdx.x;
    const int b = bid >> 5;
    const int qblk = bid & 31;
    const int q0 = qblk * 64 + wv * 16;
    const int vlen = vlens[b];
    const int kmax = (vlen > 0) ? vlen : NL;
    const int ntiles = (kmax + KT - 1) / KT;

    bfrag qh[4], ql[4];
    {
        const float* qp = Qg + ((size_t)b * NL + (size_t)(q0 + lq)) * ND + lg * 8;
        #pragma unroll
        for (int s = 0; s < 4; ++s) {
            f32x4 a0 = *(const f32x4*)(qp + s * 32);
            f32x4 a1 = *(const f32x4*)(qp + s * 32 + 4);
            float vals[8] = {a0[0], a0[1], a0[2], a0[3], a1[0], a1[1], a1[2], a1[3]};
            bfrag h, l;
            #pragma unroll
            for (int j = 0; j < 8; ++j) {
                short hb = f2bf(vals[j]);
                h[j] = hb;
                l[j] = f2bf(vals[j] - bf2f(hb));
            }
            qh[s] = h; ql[s] = l;
        }
    }

    const f32x4 zero4 = {0.f, 0.f, 0.f, 0.f};
    float m_run = -INFINITY, l_run = 0.0f;
    f32x4 oacc[8];
    #pragma unroll
    for (int i = 0; i < 8; ++i) oacc[i] = zero4;

    const float* kbase = Kg + (size_t)b * NL * ND;
    const float* vbase = Vg + (size_t)b * NL * ND;

    for (int t = 0; t < ntiles; ++t) {
        const int kt0 = t * KT;
        __syncthreads();
        #pragma unroll
        for (int i = 0; i < 4; ++i) {
            int f = i * 256 + tid;
            int r = f >> 5, c4 = (f & 31) << 2;
            f32x4 v = *(const f32x4*)(kbase + (size_t)(kt0 + r) * ND + c4);
            s16x4 hh, ll;
            #pragma unroll
            for (int j = 0; j < 4; ++j) {
                short hb = f2bf(v[j]);
                hh[j] = hb;
                ll[j] = f2bf(v[j] - bf2f(hb));
            }
            int idx = kswz(r, c4);
            *(s16x4*)&kh[idx] = hh;
            *(s16x4*)&kl[idx] = ll;
        }
        #pragma unroll
        for (int i = 0; i < 4; ++i) {
            int tau = i * 256 + tid;
            int c = tau & 127, kq = (tau >> 7) << 2;
            s16x4 hh, ll;
            #pragma unroll
            for (int j = 0; j < 4; ++j) {
                float fv = vbase[(size_t)(kt0 + kq + j) * ND + c];
                short hb = f2bf(fv);
                hh[j] = hb;
                ll[j] = f2bf(fv - bf2f(hb));
            }
            int idx = vswz(c, kq);
            *(s16x4*)&vth[idx] = hh;
            *(s16x4*)&vtl[idx] = ll;
        }
        __syncthreads();

        f32x4 sacc[2];
        sacc[0] = zero4; sacc[1] = zero4;
        #pragma unroll
        for (int sub = 0; sub < 2; ++sub) {
            #pragma unroll
            for (int s = 0; s < 4; ++s) {
                int ia = kswz(sub * 16 + lq, s * 32 + lg * 8);
                bfrag ah = *(const bfrag*)&kh[ia];
                bfrag al = *(const bfrag*)&kl[ia];
                sacc[sub] = __builtin_amdgcn_mfma_f32_16x16x32_bf16(ah, qh[s], sacc[sub], 0, 0, 0);
                sacc[sub] = __builtin_amdgcn_mfma_f32_16x16x32_bf16(al, qh[s], sacc[sub], 0, 0, 0);
                sacc[sub] = __builtin_amdgcn_mfma_f32_16x16x32_bf16(ah, ql[s], sacc[sub], 0, 0, 0);
            }
        }

        float sv[2][4];
        float tmax = -INFINITY;
        #pragma unroll
        for (int sub = 0; sub < 2; ++sub)
            #pragma unroll
            for (int r = 0; r < 4; ++r) {
                int kg = kt0 + sub * 16 + lg * 4 + r;
                float x = (kg < vlen) ? sacc[sub][r] * SCL : NEGV;
                sv[sub][r] = x;
                tmax = fmaxf(tmax, x);
            }
        tmax = fmaxf(tmax, __shfl_xor(tmax, 16, 64));
        tmax = fmaxf(tmax, __shfl_xor(tmax, 32, 64));
        float m_new = fmaxf(m_run, tmax);
        float corr = __expf(m_run - m_new);
        float rsum = 0.f;
        s16x4 phv[2], plv[2];
        #pragma unroll
        for (int sub = 0; sub < 2; ++sub)
            #pragma unroll
            for (int r = 0; r < 4; ++r) {
                float p = __expf(sv[sub][r] - m_new);
                rsum += p;
                short hb = f2bf(p);
                phv[sub][r] = hb;
                plv[sub][r] = f2bf(p - bf2f(hb));
            }
        rsum += __shfl_xor(rsum, 16, 64);
        rsum += __shfl_xor(rsum, 32, 64);
        l_run = l_run * corr + rsum;
        m_run = m_new;
        #pragma unroll
        for (int i = 0; i < 8; ++i) {
            oacc[i][0] *= corr; oacc[i][1] *= corr;
            oacc[i][2] *= corr; oacc[i][3] *= corr;
        }

        #pragma unroll
        for (int sub = 0; sub < 2; ++sub) {
            int ip = pswz(lq, sub * 16 + lg * 4);
            *(s16x4*)&ph[wv][ip] = phv[sub];
            *(s16x4*)&pl[wv][ip] = plv[sub];
        }
        int ipb = pswz(lq, lg * 8);
        bfrag pbh = *(const bfrag*)&ph[wv][ipb];
        bfrag pbl = *(const bfrag*)&pl[wv][ipb];
        #pragma unroll
        for (int dt = 0; dt < 8; ++dt) {
            int iv = vswz(dt * 16 + lq, lg * 8);
            bfrag vh  = *(const bfrag*)&vth[iv];
            bfrag vlo = *(const bfrag*)&vtl[iv];
            oacc[dt] = __builtin_amdgcn_mfma_f32_16x16x32_bf16(vh,  pbh, oacc[dt], 0, 0, 0);
            oacc[dt] = __builtin_amdgcn_mfma_f32_16x16x32_bf16(vlo, pbh, oacc[dt], 0, 0, 0);
            oacc[dt] = __builtin_amdgcn_mfma_f32_16x16x32_bf16(vh,  pbl, oacc[dt], 0, 0, 0);
        }
    }

    float inv = 1.0f / l_run;
    float* op = Og + ((size_t)b * NL + (size_t)(q0 + lq)) * ND + lg * 4;
    #pragma unroll
    for (int dt = 0; dt < 8; ++dt) {
        f32x4 o;
        o[0] = oacc[dt][0] * inv; o[1] = oacc[dt][1] * inv;
        o[2] = oacc[dt][2] * inv; o[3] = oacc[dt][3] * inv;
        *(f32x4*)(op + dt * 16) = o;
    }
}

extern "C" void kernel_launch(void* const* d_in, const int* in_sizes, int n_in,
                              void* d_out, int out_size, void* d_ws, size_t ws_size,
                              hipStream_t stream) {
    (void)in_sizes; (void)n_in; (void)out_size;
    const float* Q = (const float*)d_in[0];
    const float* K = (const float*)d_in[1];
    const float* V = (const float*)d_in[2];
    const int* vl  = (const int*)d_in[3];
    float* O = (float*)d_out;

    const size_t tensor_shorts = (size_t)NB * NTILE * 8192;            // 16.78 MB each
    const size_t kv_bytes = 2 * tensor_shorts * sizeof(short);         // 33.55 MB
    const size_t unit_bytes = 16640 * sizeof(float);                   // 66.56 KB
    const size_t pws4 = (size_t)NB * 16 * 4 * unit_bytes;              // 68.2 MB
    const size_t pws2 = (size_t)NB * 16 * 2 * unit_bytes;              // 34.1 MB

    short* KWS = (short*)d_ws;
    short* VWS = KWS + tensor_shorts;
    float* PWS = (float*)((char*)d_ws + kv_bytes);

    if (ws_size >= kv_bytes + pws4) {
        prep_kv<<<dim3(NB * NTILE * 2), dim3(512), 0, stream>>>(K, V, vl, KWS, VWS);
        attn_split8<4><<<dim3(NB * 16 * 4), dim3(512), 0, stream>>>(Q, vl, KWS, VWS, PWS);
        merge_part8<4><<<dim3(NB * 16), dim3(256), 0, stream>>>(vl, PWS, O);
    } else if (ws_size >= kv_bytes + pws2) {
        prep_kv<<<dim3(NB * NTILE * 2), dim3(512), 0, stream>>>(K, V, vl, KWS, VWS);
        attn_split8<2><<<dim3(NB * 16 * 2), dim3(512), 0, stream>>>(Q, vl, KWS, VWS, PWS);
        merge_part8<2><<<dim3(NB * 16), dim3(256), 0, stream>>>(vl, PWS, O);
    } else if (ws_size >= kv_bytes) {
        prep_kv<<<dim3(NB * NTILE * 2), dim3(512), 0, stream>>>(K, V, vl, KWS, VWS);
        attn_fwd<<<dim3(NB * 32), dim3(256), 0, stream>>>(Q, vl, KWS, VWS, O);
    } else {
        attn_fwd_fb<<<dim3(NB * 32), dim3(256), 0, stream>>>(Q, K, V, vl, O);
    }
}